// Round 1
// baseline (160.784 us; speedup 1.0000x reference)
//
#include <hip/hip_runtime.h>

typedef _Float16 f16;
typedef _Float16 f16x2 __attribute__((ext_vector_type(2)));
typedef _Float16 f16x4 __attribute__((ext_vector_type(4)));
typedef _Float16 f16x8 __attribute__((ext_vector_type(8)));
typedef float f32x4 __attribute__((ext_vector_type(4)));
typedef float f32x16 __attribute__((ext_vector_type(16)));
typedef unsigned int u32;
typedef unsigned int u32x4 __attribute__((ext_vector_type(4)));

__device__ inline f32x16 mfma32(f16x8 a, f16x8 b, f32x16 c) {
    return __builtin_amdgcn_mfma_f32_32x32x16_f16(a, b, c, 0, 0, 0);
}

__device__ inline u32 pk2u(float a, float b) {
    return __builtin_bit_cast(u32, __builtin_amdgcn_cvt_pkrtz(a, b));
}

// ---------------------------------------------------------------------------
// Kernel 1: merged prep. blocks [0,1536): weight norm -> w f16.
//           blocks [1536, 5632): transpose x (B,C,N) fp32 -> xT (B,N,C) f16.
// ---------------------------------------------------------------------------
__global__ __launch_bounds__(256) void prep_k(const float* __restrict__ pv,
                                              const float* __restrict__ pg,
                                              f16* __restrict__ w,
                                              const float* __restrict__ x,
                                              f16* __restrict__ xT) {
    int bid = blockIdx.x;
    if (bid < 1536) {
        int o = bid;
        const float* row = pv + (size_t)o * 512;
        float s = 0.f;
        for (int c = threadIdx.x; c < 512; c += 256) { float t = row[c]; s += t * t; }
        for (int off = 32; off; off >>= 1) s += __shfl_down(s, off, 64);
        __shared__ float red[4];
        int lane = threadIdx.x & 63, wid = threadIdx.x >> 6;
        if (lane == 0) red[wid] = s;
        __syncthreads();
        float tot = red[0] + red[1] + red[2] + red[3];
        float scale = pg[o] * rsqrtf(tot);
        for (int c = threadIdx.x; c < 512; c += 256)
            w[(size_t)o * 512 + c] = (f16)(row[c] * scale);
    } else {
        int t2 = bid - 1536;
        int n0 = (t2 & 31) * 32, c0 = ((t2 >> 5) & 15) * 32, b = t2 >> 9;
        int tx = threadIdx.x & 31, ty = threadIdx.x >> 5;  // 32 x 8
        __shared__ float t[32][33];
        const float* xb = x + (size_t)b * 512 * 1024;
        for (int i = 0; i < 4; i++)
            t[ty + 8 * i][tx] = xb[(size_t)(c0 + ty + 8 * i) * 1024 + n0 + tx];
        __syncthreads();
        f16* xTb = xT + (size_t)b * 1024 * 512;
        for (int i = 0; i < 4; i++)
            xTb[(size_t)(n0 + ty + 8 * i) * 512 + c0 + tx] = (f16)t[tx][ty + 8 * i];
    }
}

// ---------------------------------------------------------------------------
// Kernel 3: QKV GEMM, 32x32x16 MFMA core, single-buffer BK=64 + register
//   prefetch, XOR-swizzled unpadded LDS (frozen: R8/R9 state).
// ---------------------------------------------------------------------------
__global__ __launch_bounds__(256) void qkv_gemm_k(const f16* __restrict__ w,
                                                  const f16* __restrict__ xT,
                                                  const float* __restrict__ pb,
                                                  f16* __restrict__ qk,
                                                  f16* __restrict__ v) {
    __shared__ f16 lA[128 * 64];   // 16 KB
    __shared__ f16 lB[128 * 64];   // 16 KB
    int b = blockIdx.z;
    int oBase = blockIdx.y * 128;
    int nBase = blockIdx.x * 128;
    const f16* xb = xT + (size_t)b * 1024 * 512;
    int tid = threadIdx.x, lane = tid & 63, warp = tid >> 6;
    int wy = warp >> 1, wx = warp & 1;
    int l31 = lane & 31, hi = lane >> 5;

    int srow = lane >> 3;
    int phys = lane & 7;
    int schunk = phys ^ srow;
    const f16* aS[4]; const f16* bS[4]; int ldsOff[4];
    for (int j = 0; j < 4; j++) {
        int rb = (warp * 4 + j) * 8;
        aS[j] = w  + (size_t)(oBase + rb + srow) * 512 + schunk * 8;
        bS[j] = xb + (size_t)(nBase + rb + srow) * 512 + schunk * 8;
        ldsOff[j] = (rb + srow) * 64 + phys * 8;
    }
    int phk[4];
    for (int ks = 0; ks < 4; ks++)
        phk[ks] = (((ks * 2 + hi) ^ (l31 & 7))) * 8;

    f16x8 rA[4], rB[4];
    for (int j = 0; j < 4; j++) {
        rA[j] = *(const f16x8*)aS[j];
        rB[j] = *(const f16x8*)bS[j];
    }

    f32x16 acc[2][2] = {};

    for (int i = 0; i < 8; i++) {
        __syncthreads();
        for (int j = 0; j < 4; j++) {
            *(f16x8*)&lA[ldsOff[j]] = rA[j];
            *(f16x8*)&lB[ldsOff[j]] = rB[j];
        }
        __syncthreads();
        if (i < 7) {
            int k0 = (i + 1) * 64;
            for (int j = 0; j < 4; j++) {
                rA[j] = *(const f16x8*)(aS[j] + k0);
                rB[j] = *(const f16x8*)(bS[j] + k0);
            }
        }
        for (int ks = 0; ks < 4; ks++) {
            f16x8 af[2], bf[2];
            for (int mi = 0; mi < 2; mi++)
                af[mi] = *(f16x8*)&lA[(wy * 64 + mi * 32 + l31) * 64 + phk[ks]];
            for (int ni = 0; ni < 2; ni++)
                bf[ni] = *(f16x8*)&lB[(wx * 64 + ni * 32 + l31) * 64 + phk[ks]];
            for (int mi = 0; mi < 2; mi++)
                for (int ni = 0; ni < 2; ni++)
                    acc[mi][ni] = mfma32(af[mi], bf[ni], acc[mi][ni]);
        }
    }

    int selB = oBase >> 9;
    for (int mi = 0; mi < 2; mi++) {
        for (int g = 0; g < 4; g++) {
            int oR = oBase + wy * 64 + mi * 32 + 8 * g + 4 * hi;
            int h = (oR >> 6) & 7, d0 = oR & 63;
            for (int ni = 0; ni < 2; ni++) {
                int n = nBase + wx * 64 + ni * 32 + l31;
                if (selB < 2) {
                    float sc = selB == 0 ? 0.125f : 1.0f;  // fold 1/sqrt(64)
                    f16x4 o4;
                    for (int r = 0; r < 4; r++)
                        o4[r] = (f16)((acc[mi][ni][g * 4 + r] + pb[oR + r]) * sc);
                    *(f16x4*)&qk[((((size_t)b * 2 + selB) * 8 + h) * 1024 + n) * 64 + d0] = o4;
                } else {
                    for (int r = 0; r < 4; r++) {
                        float val = acc[mi][ni][g * 4 + r] + pb[oR + r];
                        v[(((size_t)b * 8 + h) * 64 + d0 + r) * 1024 + n] = (f16)val;
                    }
                }
            }
        }
    }
}

// ---------------------------------------------------------------------------
// Kernel 4: fused attention + residual. 32x32x16 core, wave owns 32 q,
//   block = 128 q (4 waves).
//   R-new: LDS-FREE. K/V per (b,h) is only 256 KB (L2-fit regime, m169):
//   fragments are lane-addressable directly from global (16 B/lane, each
//   128 B line fully consumed across the ks loop, 4-wave reuse via L1).
//   Removes all DS staging (~48 DS instr/wave/kt) and BOTH barriers/kt.
//   Grid swapped to dim3(64, 8): bh on blockIdx.x so the 8 q-blocks of a
//   given (b,h) land on the SAME XCD (64 = 0 mod 8); 8 bh x 256 KB = 2 MB
//   fits the 4 MB per-XCD L2.
//   P stays in registers; PV B-frag assembled via one shfl_xor(32) pair
//   per ks.  No online max (scores bounded); l reduced at epilogue.
// ---------------------------------------------------------------------------
__global__ __launch_bounds__(256, 2) void attn_k(const f16* __restrict__ qk,
                                                 const f16* __restrict__ vg,
                                                 const float* __restrict__ x,
                                                 float* __restrict__ out) {
    int bh = blockIdx.x;
    int b = bh >> 3, h = bh & 7;
    int qBase = blockIdx.y * 128;
    int tid = threadIdx.x, lane = tid & 63, warp = tid >> 6;
    int l31 = lane & 31, hi = lane >> 5;

    const f16* qbase = qk + (((size_t)b * 2 + 0) * 8 + h) * 1024 * 64;
    const f16* kbase = qk + (((size_t)b * 2 + 1) * 8 + h) * 1024 * 64;
    const f16* vbase = vg + ((size_t)b * 8 + h) * 64 * 1024;

    int q0 = qBase + warp * 32;
    f16x8 aq[4];
    for (int ks = 0; ks < 4; ks++)
        aq[ks] = *(const f16x8*)&qbase[(size_t)(q0 + l31) * 64 + ks * 16 + hi * 8];

    f32x16 accO[2] = {};
    float l_acc = 0.f;

    for (int kt = 0; kt < 16; kt++) {
        const f16* kb = kbase + (size_t)kt * 64 * 64;

        // S^T per mt; p = exp(s) packed to f16x2 pairs in registers:
        // P0[mt][g] = k-pair {8g+4hi+0,1}, P1 = {8g+4hi+2,3} (col q = l31)
        u32 P0[2][4], P1[2][4];
        float rs = 0.f;
        for (int mt = 0; mt < 2; mt++) {
            f16x8 ak[4];
            for (int ks = 0; ks < 4; ks++)
                ak[ks] = *(const f16x8*)&kb[(size_t)(mt * 32 + l31) * 64 + ks * 16 + hi * 8];
            f32x16 stt = {};
            for (int ks = 0; ks < 4; ks++)
                stt = mfma32(ak[ks], aq[ks], stt);
            for (int g = 0; g < 4; g++) {
                float p0 = __expf(stt[g * 4 + 0]);
                float p1 = __expf(stt[g * 4 + 1]);
                float p2 = __expf(stt[g * 4 + 2]);
                float p3 = __expf(stt[g * 4 + 3]);
                rs += (p0 + p1) + (p2 + p3);
                P0[mt][g] = pk2u(p0, p1);
                P1[mt][g] = pk2u(p2, p3);
            }
        }
        l_acc += rs;

        // PV: B-frag for ks: mt=ks>>1; j0-3 from lane (q,0), j4-7 from (q,1),
        // both with g = 2(ks&1)+hi_dest.  Send g = 2(ks&1)+(hi^1).
        f16x8 av[2][4];
        for (int dt = 0; dt < 2; dt++)
            for (int ks = 0; ks < 4; ks++)
                av[dt][ks] = *(const f16x8*)&vbase[(size_t)(dt * 32 + l31) * 1024 + kt * 64 + ks * 16 + hi * 8];
        f16x8 bfrag[4];
        for (int ks = 0; ks < 4; ks++) {
            int mt = ks >> 1, ge = 2 * (ks & 1);
            u32 e00 = P0[mt][ge], e01 = P0[mt][ge + 1];
            u32 e10 = P1[mt][ge], e11 = P1[mt][ge + 1];
            u32 k0 = hi ? e01 : e00;       // keep: g = ge + hi
            u32 k1 = hi ? e11 : e10;
            u32 s0 = hi ? e00 : e01;       // send: g = ge + (hi^1)
            u32 s1 = hi ? e10 : e11;
            u32 r0 = __shfl_xor(s0, 32, 64);
            u32 r1 = __shfl_xor(s1, 32, 64);
            u32 a0 = hi ? r0 : k0, a1 = hi ? r1 : k1;   // from (q,0)
            u32 b0 = hi ? k0 : r0, b1 = hi ? k1 : r1;   // from (q,1)
            u32x4 t = {a0, a1, b0, b1};
            bfrag[ks] = __builtin_bit_cast(f16x8, t);
        }
        for (int dt = 0; dt < 2; dt++)
            for (int ks = 0; ks < 4; ks++)
                accO[dt] = mfma32(av[dt][ks], bfrag[ks], accO[dt]);
    }

    // epilogue: l = own + partner halves; direct 2-segment coalesced stores
    float lt = l_acc + __shfl_xor(l_acc, 32, 64);
    float rl = 1.0f / lt;
    int q = q0 + l31;
    for (int dt = 0; dt < 2; dt++)
        for (int g = 0; g < 4; g++)
            for (int r = 0; r < 4; r++) {
                int d = dt * 32 + 8 * g + 4 * hi + r;
                size_t gi = ((size_t)b * 512 + h * 64 + d) * 1024 + q;
                out[gi] = x[gi] + accO[dt][g * 4 + r] * rl;
            }
}

// ---------------------------------------------------------------------------
extern "C" void kernel_launch(void* const* d_in, const int* in_sizes, int n_in,
                              void* d_out, int out_size, void* d_ws, size_t ws_size,
                              hipStream_t stream) {
    (void)in_sizes; (void)n_in; (void)out_size; (void)ws_size;
    const float* x  = (const float*)d_in[0];
    const float* pv = (const float*)d_in[1];
    const float* pg = (const float*)d_in[2];
    const float* pb = (const float*)d_in[3];
    float* out = (float*)d_out;

    char* ws = (char*)d_ws;
    f16* w   = (f16*)(ws);                                   // 1,572,864 B
    f16* xT  = (f16*)(ws + 1572864);                         // 8,388,608 B
    f16* qk  = (f16*)(ws + 1572864 + 8388608);               // 16,777,216 B
    f16* v   = (f16*)(ws + 1572864 + 8388608 + 16777216);    // 8,388,608 B

    hipLaunchKernelGGL(prep_k,     dim3(5632),     dim3(256), 0, stream, pv, pg, w, x, xT);
    hipLaunchKernelGGL(qkv_gemm_k, dim3(8, 12, 8), dim3(256), 0, stream, w, xT, pb, qk, v);
    hipLaunchKernelGGL(attn_k,     dim3(64, 8),    dim3(256), 0, stream, qk, v, x, out);
}

// Round 2
// 140.911 us; speedup vs baseline: 1.1410x; 1.1410x over previous
//
#include <hip/hip_runtime.h>

typedef _Float16 f16;
typedef _Float16 f16x2 __attribute__((ext_vector_type(2)));
typedef _Float16 f16x4 __attribute__((ext_vector_type(4)));
typedef _Float16 f16x8 __attribute__((ext_vector_type(8)));
typedef float f32x4 __attribute__((ext_vector_type(4)));
typedef float f32x16 __attribute__((ext_vector_type(16)));
typedef unsigned int u32;
typedef unsigned int u32x4 __attribute__((ext_vector_type(4)));

__device__ inline f32x16 mfma32(f16x8 a, f16x8 b, f32x16 c) {
    return __builtin_amdgcn_mfma_f32_32x32x16_f16(a, b, c, 0, 0, 0);
}

__device__ inline u32 pk2u(float a, float b) {
    return __builtin_bit_cast(u32, __builtin_amdgcn_cvt_pkrtz(a, b));
}

// 8B-granular LDS helpers (rows padded to 68 f16 = 136 B: only 8B-aligned)
__device__ inline void st8(f16* p, f16x8 v) {
    *(f16x4*)p = __builtin_shufflevector(v, v, 0, 1, 2, 3);
    *(f16x4*)(p + 4) = __builtin_shufflevector(v, v, 4, 5, 6, 7);
}
__device__ inline f16x8 ld8(const f16* p) {
    f16x4 lo = *(const f16x4*)p;
    f16x4 hi = *(const f16x4*)(p + 4);
    return __builtin_shufflevector(lo, hi, 0, 1, 2, 3, 4, 5, 6, 7);
}

// ---------------------------------------------------------------------------
// Kernel 1: merged prep. blocks [0,1536): weight norm -> w f16.
//           blocks [1536, 5632): transpose x (B,C,N) fp32 -> xT (B,N,C) f16.
// ---------------------------------------------------------------------------
__global__ __launch_bounds__(256) void prep_k(const float* __restrict__ pv,
                                              const float* __restrict__ pg,
                                              f16* __restrict__ w,
                                              const float* __restrict__ x,
                                              f16* __restrict__ xT) {
    int bid = blockIdx.x;
    if (bid < 1536) {
        int o = bid;
        const float* row = pv + (size_t)o * 512;
        float s = 0.f;
        for (int c = threadIdx.x; c < 512; c += 256) { float t = row[c]; s += t * t; }
        for (int off = 32; off; off >>= 1) s += __shfl_down(s, off, 64);
        __shared__ float red[4];
        int lane = threadIdx.x & 63, wid = threadIdx.x >> 6;
        if (lane == 0) red[wid] = s;
        __syncthreads();
        float tot = red[0] + red[1] + red[2] + red[3];
        float scale = pg[o] * rsqrtf(tot);
        for (int c = threadIdx.x; c < 512; c += 256)
            w[(size_t)o * 512 + c] = (f16)(row[c] * scale);
    } else {
        int t2 = bid - 1536;
        int n0 = (t2 & 31) * 32, c0 = ((t2 >> 5) & 15) * 32, b = t2 >> 9;
        int tx = threadIdx.x & 31, ty = threadIdx.x >> 5;  // 32 x 8
        __shared__ float t[32][33];
        const float* xb = x + (size_t)b * 512 * 1024;
        for (int i = 0; i < 4; i++)
            t[ty + 8 * i][tx] = xb[(size_t)(c0 + ty + 8 * i) * 1024 + n0 + tx];
        __syncthreads();
        f16* xTb = xT + (size_t)b * 1024 * 512;
        for (int i = 0; i < 4; i++)
            xTb[(size_t)(n0 + ty + 8 * i) * 512 + c0 + tx] = (f16)t[tx][ty + 8 * i];
    }
}

// ---------------------------------------------------------------------------
// Kernel 3: QKV GEMM, 32x32x16 MFMA core, single-buffer BK=64 + register
//   prefetch, XOR-swizzled unpadded LDS (frozen: R8/R9 state).
// ---------------------------------------------------------------------------
__global__ __launch_bounds__(256) void qkv_gemm_k(const f16* __restrict__ w,
                                                  const f16* __restrict__ xT,
                                                  const float* __restrict__ pb,
                                                  f16* __restrict__ qk,
                                                  f16* __restrict__ v) {
    __shared__ f16 lA[128 * 64];   // 16 KB
    __shared__ f16 lB[128 * 64];   // 16 KB
    int b = blockIdx.z;
    int oBase = blockIdx.y * 128;
    int nBase = blockIdx.x * 128;
    const f16* xb = xT + (size_t)b * 1024 * 512;
    int tid = threadIdx.x, lane = tid & 63, warp = tid >> 6;
    int wy = warp >> 1, wx = warp & 1;
    int l31 = lane & 31, hi = lane >> 5;

    int srow = lane >> 3;
    int phys = lane & 7;
    int schunk = phys ^ srow;
    const f16* aS[4]; const f16* bS[4]; int ldsOff[4];
    for (int j = 0; j < 4; j++) {
        int rb = (warp * 4 + j) * 8;
        aS[j] = w  + (size_t)(oBase + rb + srow) * 512 + schunk * 8;
        bS[j] = xb + (size_t)(nBase + rb + srow) * 512 + schunk * 8;
        ldsOff[j] = (rb + srow) * 64 + phys * 8;
    }
    int phk[4];
    for (int ks = 0; ks < 4; ks++)
        phk[ks] = (((ks * 2 + hi) ^ (l31 & 7))) * 8;

    f16x8 rA[4], rB[4];
    for (int j = 0; j < 4; j++) {
        rA[j] = *(const f16x8*)aS[j];
        rB[j] = *(const f16x8*)bS[j];
    }

    f32x16 acc[2][2] = {};

    for (int i = 0; i < 8; i++) {
        __syncthreads();
        for (int j = 0; j < 4; j++) {
            *(f16x8*)&lA[ldsOff[j]] = rA[j];
            *(f16x8*)&lB[ldsOff[j]] = rB[j];
        }
        __syncthreads();
        if (i < 7) {
            int k0 = (i + 1) * 64;
            for (int j = 0; j < 4; j++) {
                rA[j] = *(const f16x8*)(aS[j] + k0);
                rB[j] = *(const f16x8*)(bS[j] + k0);
            }
        }
        for (int ks = 0; ks < 4; ks++) {
            f16x8 af[2], bf[2];
            for (int mi = 0; mi < 2; mi++)
                af[mi] = *(f16x8*)&lA[(wy * 64 + mi * 32 + l31) * 64 + phk[ks]];
            for (int ni = 0; ni < 2; ni++)
                bf[ni] = *(f16x8*)&lB[(wx * 64 + ni * 32 + l31) * 64 + phk[ks]];
            for (int mi = 0; mi < 2; mi++)
                for (int ni = 0; ni < 2; ni++)
                    acc[mi][ni] = mfma32(af[mi], bf[ni], acc[mi][ni]);
        }
    }

    int selB = oBase >> 9;
    for (int mi = 0; mi < 2; mi++) {
        for (int g = 0; g < 4; g++) {
            int oR = oBase + wy * 64 + mi * 32 + 8 * g + 4 * hi;
            int h = (oR >> 6) & 7, d0 = oR & 63;
            for (int ni = 0; ni < 2; ni++) {
                int n = nBase + wx * 64 + ni * 32 + l31;
                if (selB < 2) {
                    float sc = selB == 0 ? 0.125f : 1.0f;  // fold 1/sqrt(64)
                    f16x4 o4;
                    for (int r = 0; r < 4; r++)
                        o4[r] = (f16)((acc[mi][ni][g * 4 + r] + pb[oR + r]) * sc);
                    *(f16x4*)&qk[((((size_t)b * 2 + selB) * 8 + h) * 1024 + n) * 64 + d0] = o4;
                } else {
                    for (int r = 0; r < 4; r++) {
                        float val = acc[mi][ni][g * 4 + r] + pb[oR + r];
                        v[(((size_t)b * 8 + h) * 64 + d0 + r) * 1024 + n] = (f16)val;
                    }
                }
            }
        }
    }
}

// ---------------------------------------------------------------------------
// Kernel 4: fused attention + residual. 32x32x16 core.
//   R-new: wave owns 64 q (two 32-col groups) so each ak/av LDS fragment
//   feeds 2x the MFMA work -> LDS read bytes per q HALVED (DS traffic was
//   the largest component of the proven 4-wave version).  Block = 128 thr
//   (2 waves) covering 128 q; grid unchanged 512 blocks -> 4 blocks/CU,
//   still 8 waves/CU = 2/SIMD (R9: 1/SIMD exposes MFMA latency).
//   LDS staging + register prefetch (proven structure) retained; round-1's
//   LDS-free global-direct variant was latency-bound (MfmaUtil 9%) and is
//   reverted.  P stays in registers; PV B-frag via one shfl_xor(32) pair
//   per (qs,ks).  No online max (scores bounded); l reduced at epilogue.
// ---------------------------------------------------------------------------
#define ALDK 68
__global__ __launch_bounds__(128, 2) void attn_k(const f16* __restrict__ qk,
                                                 const f16* __restrict__ vg,
                                                 const float* __restrict__ x,
                                                 float* __restrict__ out) {
    __shared__ __align__(16) f16 smem[2 * 64 * ALDK];
    f16* lK = smem;
    f16* lV = smem + 64 * ALDK;

    int bh = blockIdx.y;
    int b = bh >> 3, h = bh & 7;
    int qBase = blockIdx.x * 128;
    int tid = threadIdx.x, lane = tid & 63, warp = tid >> 6;
    int l31 = lane & 31, hi = lane >> 5;

    const f16* qbase = qk + (((size_t)b * 2 + 0) * 8 + h) * 1024 * 64;
    const f16* kbase = qk + (((size_t)b * 2 + 1) * 8 + h) * 1024 * 64;
    const f16* vbase = vg + ((size_t)b * 8 + h) * 64 * 1024;

    int q0 = qBase + warp * 64;
    f16x8 aq[2][4];
    for (int qs = 0; qs < 2; qs++)
        for (int ks = 0; ks < 4; ks++)
            aq[qs][ks] = *(const f16x8*)&qbase[(size_t)(q0 + qs * 32 + l31) * 64 + ks * 16 + hi * 8];

    // staging: 128 threads cover 64x64 tile, 4 rows each (sr, sr+16, +32, +48)
    int sr = tid >> 3, sc0 = (tid & 7) * 8;

    f16x8 rK[4], rV[4];
    for (int j = 0; j < 4; j++) {
        rK[j] = *(const f16x8*)&kbase[(size_t)(sr + 16 * j) * 64 + sc0];
        rV[j] = *(const f16x8*)&vbase[(size_t)(sr + 16 * j) * 1024 + sc0];
    }

    f32x16 accO[2][2] = {};
    float l_acc[2] = {0.f, 0.f};

    for (int kt = 0; kt < 16; kt++) {
        __syncthreads();
        for (int j = 0; j < 4; j++) {
            st8(&lK[(sr + 16 * j) * ALDK + sc0], rK[j]);
            st8(&lV[(sr + 16 * j) * ALDK + sc0], rV[j]);
        }
        __syncthreads();
        if (kt < 15) {
            const f16* kb = kbase + (size_t)(kt + 1) * 64 * 64;
            for (int j = 0; j < 4; j++) {
                rK[j] = *(const f16x8*)&kb[(size_t)(sr + 16 * j) * 64 + sc0];
                rV[j] = *(const f16x8*)&vbase[(size_t)(sr + 16 * j) * 1024 + (kt + 1) * 64 + sc0];
            }
        }

        // S^T per (mt, qs); p = exp(s) packed to f16x2 pairs in registers:
        // P0[qs][mt][g] = k-pair {8g+4hi+0,1}, P1 = {8g+4hi+2,3} (col q = l31)
        u32 P0[2][2][4], P1[2][2][4];
        float rs[2] = {0.f, 0.f};
        for (int mt = 0; mt < 2; mt++) {
            f16x8 ak[4];
            for (int ks = 0; ks < 4; ks++)
                ak[ks] = ld8(&lK[(mt * 32 + l31) * ALDK + ks * 16 + hi * 8]);
            for (int qs = 0; qs < 2; qs++) {
                f32x16 stt = {};
                for (int ks = 0; ks < 4; ks++)
                    stt = mfma32(ak[ks], aq[qs][ks], stt);
                for (int g = 0; g < 4; g++) {
                    float p0 = __expf(stt[g * 4 + 0]);
                    float p1 = __expf(stt[g * 4 + 1]);
                    float p2 = __expf(stt[g * 4 + 2]);
                    float p3 = __expf(stt[g * 4 + 3]);
                    rs[qs] += (p0 + p1) + (p2 + p3);
                    P0[qs][mt][g] = pk2u(p0, p1);
                    P1[qs][mt][g] = pk2u(p2, p3);
                }
            }
        }
        l_acc[0] += rs[0];
        l_acc[1] += rs[1];

        // PV B-frags for both q-sets first (P regs die here), then stream av.
        // For ks: mt=ks>>1; j0-3 from lane (q,0), j4-7 from (q,1),
        // both with g = 2(ks&1)+hi_dest.  Send g = 2(ks&1)+(hi^1).
        f16x8 bf[2][4];
        for (int qs = 0; qs < 2; qs++)
            for (int ks = 0; ks < 4; ks++) {
                int mt = ks >> 1, ge = 2 * (ks & 1);
                u32 e00 = P0[qs][mt][ge], e01 = P0[qs][mt][ge + 1];
                u32 e10 = P1[qs][mt][ge], e11 = P1[qs][mt][ge + 1];
                u32 k0 = hi ? e01 : e00;       // keep: g = ge + hi
                u32 k1 = hi ? e11 : e10;
                u32 s0 = hi ? e00 : e01;       // send: g = ge + (hi^1)
                u32 s1 = hi ? e10 : e11;
                u32 r0 = __shfl_xor(s0, 32, 64);
                u32 r1 = __shfl_xor(s1, 32, 64);
                u32 a0 = hi ? r0 : k0, a1 = hi ? r1 : k1;   // from (q,0)
                u32 b0 = hi ? k0 : r0, b1 = hi ? k1 : r1;   // from (q,1)
                u32x4 t = {a0, a1, b0, b1};
                bf[qs][ks] = __builtin_bit_cast(f16x8, t);
            }
        for (int dt = 0; dt < 2; dt++) {
            f16x8 av[4];
            for (int ks = 0; ks < 4; ks++)
                av[ks] = ld8(&lV[(dt * 32 + l31) * ALDK + ks * 16 + hi * 8]);
            for (int qs = 0; qs < 2; qs++)
                for (int ks = 0; ks < 4; ks++)
                    accO[qs][dt] = mfma32(av[ks], bf[qs][ks], accO[qs][dt]);
        }
    }

    // epilogue: l = own + partner halves; direct 2-segment coalesced stores
    for (int qs = 0; qs < 2; qs++) {
        float lt = l_acc[qs] + __shfl_xor(l_acc[qs], 32, 64);
        float rl = 1.0f / lt;
        int q = q0 + qs * 32 + l31;
        for (int dt = 0; dt < 2; dt++)
            for (int g = 0; g < 4; g++)
                for (int r = 0; r < 4; r++) {
                    int d = dt * 32 + 8 * g + 4 * hi + r;
                    size_t gi = ((size_t)b * 512 + h * 64 + d) * 1024 + q;
                    out[gi] = x[gi] + accO[qs][dt][g * 4 + r] * rl;
                }
    }
}

// ---------------------------------------------------------------------------
extern "C" void kernel_launch(void* const* d_in, const int* in_sizes, int n_in,
                              void* d_out, int out_size, void* d_ws, size_t ws_size,
                              hipStream_t stream) {
    (void)in_sizes; (void)n_in; (void)out_size; (void)ws_size;
    const float* x  = (const float*)d_in[0];
    const float* pv = (const float*)d_in[1];
    const float* pg = (const float*)d_in[2];
    const float* pb = (const float*)d_in[3];
    float* out = (float*)d_out;

    char* ws = (char*)d_ws;
    f16* w   = (f16*)(ws);                                   // 1,572,864 B
    f16* xT  = (f16*)(ws + 1572864);                         // 8,388,608 B
    f16* qk  = (f16*)(ws + 1572864 + 8388608);               // 16,777,216 B
    f16* v   = (f16*)(ws + 1572864 + 8388608 + 16777216);    // 8,388,608 B

    hipLaunchKernelGGL(prep_k,     dim3(5632),     dim3(256), 0, stream, pv, pg, w, x, xT);
    hipLaunchKernelGGL(qkv_gemm_k, dim3(8, 12, 8), dim3(256), 0, stream, w, xT, pb, qk, v);
    hipLaunchKernelGGL(attn_k,     dim3(8, 64),    dim3(128), 0, stream, qk, v, x, out);
}

// Round 3
// 128.860 us; speedup vs baseline: 1.2477x; 1.0935x over previous
//
#include <hip/hip_runtime.h>

typedef _Float16 f16;
typedef _Float16 f16x2 __attribute__((ext_vector_type(2)));
typedef _Float16 f16x4 __attribute__((ext_vector_type(4)));
typedef _Float16 f16x8 __attribute__((ext_vector_type(8)));
typedef float f32x4 __attribute__((ext_vector_type(4)));
typedef float f32x16 __attribute__((ext_vector_type(16)));
typedef unsigned int u32;
typedef unsigned int u32x4 __attribute__((ext_vector_type(4)));

__device__ inline f32x16 mfma32(f16x8 a, f16x8 b, f32x16 c) {
    return __builtin_amdgcn_mfma_f32_32x32x16_f16(a, b, c, 0, 0, 0);
}

__device__ inline u32 pk2u(float a, float b) {
    return __builtin_bit_cast(u32, __builtin_amdgcn_cvt_pkrtz(a, b));
}

// 8B-granular LDS helpers (rows padded to 68 f16 = 136 B: only 8B-aligned)
__device__ inline void st8(f16* p, f16x8 v) {
    *(f16x4*)p = __builtin_shufflevector(v, v, 0, 1, 2, 3);
    *(f16x4*)(p + 4) = __builtin_shufflevector(v, v, 4, 5, 6, 7);
}
__device__ inline f16x8 ld8(const f16* p) {
    f16x4 lo = *(const f16x4*)p;
    f16x4 hi = *(const f16x4*)(p + 4);
    return __builtin_shufflevector(lo, hi, 0, 1, 2, 3, 4, 5, 6, 7);
}

// ---------------------------------------------------------------------------
// Kernel 1: merged prep. blocks [0,1536): weight norm -> w f16.
//           blocks [1536, 5632): transpose x (B,C,N) fp32 -> xT (B,N,C) f16.
// ---------------------------------------------------------------------------
__global__ __launch_bounds__(256) void prep_k(const float* __restrict__ pv,
                                              const float* __restrict__ pg,
                                              f16* __restrict__ w,
                                              const float* __restrict__ x,
                                              f16* __restrict__ xT) {
    int bid = blockIdx.x;
    if (bid < 1536) {
        int o = bid;
        const float* row = pv + (size_t)o * 512;
        float s = 0.f;
        for (int c = threadIdx.x; c < 512; c += 256) { float t = row[c]; s += t * t; }
        for (int off = 32; off; off >>= 1) s += __shfl_down(s, off, 64);
        __shared__ float red[4];
        int lane = threadIdx.x & 63, wid = threadIdx.x >> 6;
        if (lane == 0) red[wid] = s;
        __syncthreads();
        float tot = red[0] + red[1] + red[2] + red[3];
        float scale = pg[o] * rsqrtf(tot);
        for (int c = threadIdx.x; c < 512; c += 256)
            w[(size_t)o * 512 + c] = (f16)(row[c] * scale);
    } else {
        int t2 = bid - 1536;
        int n0 = (t2 & 31) * 32, c0 = ((t2 >> 5) & 15) * 32, b = t2 >> 9;
        int tx = threadIdx.x & 31, ty = threadIdx.x >> 5;  // 32 x 8
        __shared__ float t[32][33];
        const float* xb = x + (size_t)b * 512 * 1024;
        for (int i = 0; i < 4; i++)
            t[ty + 8 * i][tx] = xb[(size_t)(c0 + ty + 8 * i) * 1024 + n0 + tx];
        __syncthreads();
        f16* xTb = xT + (size_t)b * 1024 * 512;
        for (int i = 0; i < 4; i++)
            xTb[(size_t)(n0 + ty + 8 * i) * 512 + c0 + tx] = (f16)t[tx][ty + 8 * i];
    }
}

// ---------------------------------------------------------------------------
// Kernel 3: QKV GEMM, 32x32x16 MFMA core, single-buffer BK=64 + register
//   prefetch, XOR-swizzled unpadded LDS (frozen: R8/R9 state).
// ---------------------------------------------------------------------------
__global__ __launch_bounds__(256) void qkv_gemm_k(const f16* __restrict__ w,
                                                  const f16* __restrict__ xT,
                                                  const float* __restrict__ pb,
                                                  f16* __restrict__ qk,
                                                  f16* __restrict__ v) {
    __shared__ f16 lA[128 * 64];   // 16 KB
    __shared__ f16 lB[128 * 64];   // 16 KB
    int b = blockIdx.z;
    int oBase = blockIdx.y * 128;
    int nBase = blockIdx.x * 128;
    const f16* xb = xT + (size_t)b * 1024 * 512;
    int tid = threadIdx.x, lane = tid & 63, warp = tid >> 6;
    int wy = warp >> 1, wx = warp & 1;
    int l31 = lane & 31, hi = lane >> 5;

    int srow = lane >> 3;
    int phys = lane & 7;
    int schunk = phys ^ srow;
    const f16* aS[4]; const f16* bS[4]; int ldsOff[4];
    for (int j = 0; j < 4; j++) {
        int rb = (warp * 4 + j) * 8;
        aS[j] = w  + (size_t)(oBase + rb + srow) * 512 + schunk * 8;
        bS[j] = xb + (size_t)(nBase + rb + srow) * 512 + schunk * 8;
        ldsOff[j] = (rb + srow) * 64 + phys * 8;
    }
    int phk[4];
    for (int ks = 0; ks < 4; ks++)
        phk[ks] = (((ks * 2 + hi) ^ (l31 & 7))) * 8;

    f16x8 rA[4], rB[4];
    for (int j = 0; j < 4; j++) {
        rA[j] = *(const f16x8*)aS[j];
        rB[j] = *(const f16x8*)bS[j];
    }

    f32x16 acc[2][2] = {};

    for (int i = 0; i < 8; i++) {
        __syncthreads();
        for (int j = 0; j < 4; j++) {
            *(f16x8*)&lA[ldsOff[j]] = rA[j];
            *(f16x8*)&lB[ldsOff[j]] = rB[j];
        }
        __syncthreads();
        if (i < 7) {
            int k0 = (i + 1) * 64;
            for (int j = 0; j < 4; j++) {
                rA[j] = *(const f16x8*)(aS[j] + k0);
                rB[j] = *(const f16x8*)(bS[j] + k0);
            }
        }
        for (int ks = 0; ks < 4; ks++) {
            f16x8 af[2], bf[2];
            for (int mi = 0; mi < 2; mi++)
                af[mi] = *(f16x8*)&lA[(wy * 64 + mi * 32 + l31) * 64 + phk[ks]];
            for (int ni = 0; ni < 2; ni++)
                bf[ni] = *(f16x8*)&lB[(wx * 64 + ni * 32 + l31) * 64 + phk[ks]];
            for (int mi = 0; mi < 2; mi++)
                for (int ni = 0; ni < 2; ni++)
                    acc[mi][ni] = mfma32(af[mi], bf[ni], acc[mi][ni]);
        }
    }

    int selB = oBase >> 9;
    for (int mi = 0; mi < 2; mi++) {
        for (int g = 0; g < 4; g++) {
            int oR = oBase + wy * 64 + mi * 32 + 8 * g + 4 * hi;
            int h = (oR >> 6) & 7, d0 = oR & 63;
            for (int ni = 0; ni < 2; ni++) {
                int n = nBase + wx * 64 + ni * 32 + l31;
                if (selB < 2) {
                    float sc = selB == 0 ? 0.125f : 1.0f;  // fold 1/sqrt(64)
                    f16x4 o4;
                    for (int r = 0; r < 4; r++)
                        o4[r] = (f16)((acc[mi][ni][g * 4 + r] + pb[oR + r]) * sc);
                    *(f16x4*)&qk[((((size_t)b * 2 + selB) * 8 + h) * 1024 + n) * 64 + d0] = o4;
                } else {
                    for (int r = 0; r < 4; r++) {
                        float val = acc[mi][ni][g * 4 + r] + pb[oR + r];
                        v[(((size_t)b * 8 + h) * 64 + d0 + r) * 1024 + n] = (f16)val;
                    }
                }
            }
        }
    }
}

// ---------------------------------------------------------------------------
// Kernel 4: fused attention + residual. 32x32x16 core.
//   R-new: split-kv.  Block = 256 thr (4 waves) = 2 q-groups x 2 kv-halves:
//   wave (wq,wk) owns q[wq*64..+64) and kt in [wk*8, wk*8+8).  Keeps the
//   64q/wave fragment amortization (each ak/av feeds 2 q-groups -> DS
//   reads per q halved) AND restores 2048 waves = 8 waves/CU = 2/SIMD
//   (round-2's 1/SIMD was latency-bound: MfmaUtil 12.8, Occ 8.6%).
//   No online max -> partial O and l combine by plain addition at the end
//   via the dead staging LDS; wave pairs exchange the dt-half they don't
//   output (all accO indices compile-time via uniform wk branch).
//   Grid dim3(64,8): bh on x so each XCD sees bh = const (mod 8) -> K/V
//   working set 2 MB fits per-XCD L2 (round-2's (8,64) fetched 78 MB).
// ---------------------------------------------------------------------------
#define ALDK 68
#define HT (64 * ALDK)
__global__ __launch_bounds__(256, 2) void attn_k(const f16* __restrict__ qk,
                                                 const f16* __restrict__ vg,
                                                 const float* __restrict__ x,
                                                 float* __restrict__ out) {
    __shared__ __align__(16) f16 smem[4 * HT];   // 34816 B
    int bh = blockIdx.x;
    int b = bh >> 3, h = bh & 7;
    int qBase = blockIdx.y * 128;
    int tid = threadIdx.x, lane = tid & 63, warp = tid >> 6;
    int wq = warp & 1, wk = warp >> 1;
    int l31 = lane & 31, hi = lane >> 5;

    const f16* qbase = qk + (((size_t)b * 2 + 0) * 8 + h) * 1024 * 64;
    const f16* kbase = qk + (((size_t)b * 2 + 1) * 8 + h) * 1024 * 64;
    const f16* vbase = vg + ((size_t)b * 8 + h) * 64 * 1024;

    int q0 = qBase + wq * 64;
    f16x8 aq[2][4];
    for (int qs = 0; qs < 2; qs++)
        for (int ks = 0; ks < 4; ks++)
            aq[qs][ks] = *(const f16x8*)&qbase[(size_t)(q0 + qs * 32 + l31) * 64 + ks * 16 + hi * 8];

    // staging: 256 threads cover each 64x64 tile with 2 rows/thread.
    // tiles: 0=K(half0) 1=V(half0) 2=K(half1) 3=V(half1)
    int sr = tid >> 3, sc0 = (tid & 7) * 8;
    f16* myK = smem + wk * 2 * HT;
    f16* myV = myK + HT;

    f16x8 rg[4][2];
    for (int j = 0; j < 2; j++) {
        int r = sr + 32 * j;
        rg[0][j] = *(const f16x8*)&kbase[(size_t)r * 64 + sc0];
        rg[1][j] = *(const f16x8*)&vbase[(size_t)r * 1024 + sc0];
        rg[2][j] = *(const f16x8*)&kbase[(size_t)(8 * 64 + r) * 64 + sc0];
        rg[3][j] = *(const f16x8*)&vbase[(size_t)r * 1024 + 8 * 64 + sc0];
    }

    f32x16 accO[2][2] = {};
    float l_acc[2] = {0.f, 0.f};

    for (int i = 0; i < 8; i++) {
        __syncthreads();
        for (int j = 0; j < 2; j++) {
            int r = sr + 32 * j;
            st8(&smem[0 * HT + r * ALDK + sc0], rg[0][j]);
            st8(&smem[1 * HT + r * ALDK + sc0], rg[1][j]);
            st8(&smem[2 * HT + r * ALDK + sc0], rg[2][j]);
            st8(&smem[3 * HT + r * ALDK + sc0], rg[3][j]);
        }
        __syncthreads();
        if (i < 7) {
            const f16* kb0 = kbase + (size_t)(i + 1) * 64 * 64;
            const f16* kb1 = kbase + (size_t)(i + 9) * 64 * 64;
            for (int j = 0; j < 2; j++) {
                int r = sr + 32 * j;
                rg[0][j] = *(const f16x8*)&kb0[(size_t)r * 64 + sc0];
                rg[1][j] = *(const f16x8*)&vbase[(size_t)r * 1024 + (i + 1) * 64 + sc0];
                rg[2][j] = *(const f16x8*)&kb1[(size_t)r * 64 + sc0];
                rg[3][j] = *(const f16x8*)&vbase[(size_t)r * 1024 + (i + 9) * 64 + sc0];
            }
        }

        // S^T per (mt, qs); p = exp(s) packed to f16x2 pairs in registers:
        // P0[qs][mt][g] = k-pair {8g+4hi+0,1}, P1 = {8g+4hi+2,3} (col q = l31)
        u32 P0[2][2][4], P1[2][2][4];
        float rs[2] = {0.f, 0.f};
        for (int mt = 0; mt < 2; mt++) {
            f16x8 ak[4];
            for (int ks = 0; ks < 4; ks++)
                ak[ks] = ld8(&myK[(mt * 32 + l31) * ALDK + ks * 16 + hi * 8]);
            for (int qs = 0; qs < 2; qs++) {
                f32x16 stt = {};
                for (int ks = 0; ks < 4; ks++)
                    stt = mfma32(ak[ks], aq[qs][ks], stt);
                for (int g = 0; g < 4; g++) {
                    float p0 = __expf(stt[g * 4 + 0]);
                    float p1 = __expf(stt[g * 4 + 1]);
                    float p2 = __expf(stt[g * 4 + 2]);
                    float p3 = __expf(stt[g * 4 + 3]);
                    rs[qs] += (p0 + p1) + (p2 + p3);
                    P0[qs][mt][g] = pk2u(p0, p1);
                    P1[qs][mt][g] = pk2u(p2, p3);
                }
            }
        }
        l_acc[0] += rs[0];
        l_acc[1] += rs[1];

        // PV B-frags for both q-sets first (P regs die here), then stream av.
        f16x8 bf[2][4];
        for (int qs = 0; qs < 2; qs++)
            for (int ks = 0; ks < 4; ks++) {
                int mt = ks >> 1, ge = 2 * (ks & 1);
                u32 e00 = P0[qs][mt][ge], e01 = P0[qs][mt][ge + 1];
                u32 e10 = P1[qs][mt][ge], e11 = P1[qs][mt][ge + 1];
                u32 k0 = hi ? e01 : e00;       // keep: g = ge + hi
                u32 k1 = hi ? e11 : e10;
                u32 s0 = hi ? e00 : e01;       // send: g = ge + (hi^1)
                u32 s1 = hi ? e10 : e11;
                u32 r0 = __shfl_xor(s0, 32, 64);
                u32 r1 = __shfl_xor(s1, 32, 64);
                u32 a0 = hi ? r0 : k0, a1 = hi ? r1 : k1;   // from (q,0)
                u32 b0 = hi ? k0 : r0, b1 = hi ? k1 : r1;   // from (q,1)
                u32x4 t = {a0, a1, b0, b1};
                bf[qs][ks] = __builtin_bit_cast(f16x8, t);
            }
        for (int dt = 0; dt < 2; dt++) {
            f16x8 av[4];
            for (int ks = 0; ks < 4; ks++)
                av[ks] = ld8(&myV[(dt * 32 + l31) * ALDK + ks * 16 + hi * 8]);
            for (int qs = 0; qs < 2; qs++)
                for (int ks = 0; ks < 4; ks++)
                    accO[qs][dt] = mfma32(av[ks], bf[qs][ks], accO[qs][dt]);
        }
    }

    // --- cross-wave combine through (dead) staging LDS -----------------------
    // Wave (wq,wk) outputs dt=wk.  It writes accO[qs][wk^1] for its partner
    // (wq,wk^1), reads the partner's write to complete accO[qs][wk].
    // 256 slots x 34 f32 = 34816 B = exactly smem.  l exchanged alongside.
    __syncthreads();
    float* cbuf = (float*)smem;
    float* pw = cbuf + (size_t)(warp * 64 + lane) * 34;
    if (wk == 0) {
        for (int qs = 0; qs < 2; qs++)
            for (int r = 0; r < 16; r++) pw[qs * 16 + r] = accO[qs][1][r];
    } else {
        for (int qs = 0; qs < 2; qs++)
            for (int r = 0; r < 16; r++) pw[qs * 16 + r] = accO[qs][0][r];
    }
    pw[32] = l_acc[0]; pw[33] = l_acc[1];
    __syncthreads();
    const float* pr = cbuf + (size_t)((warp ^ 2) * 64 + lane) * 34;
    float o[2][16];
    if (wk == 0) {
        for (int qs = 0; qs < 2; qs++)
            for (int r = 0; r < 16; r++) o[qs][r] = accO[qs][0][r] + pr[qs * 16 + r];
    } else {
        for (int qs = 0; qs < 2; qs++)
            for (int r = 0; r < 16; r++) o[qs][r] = accO[qs][1][r] + pr[qs * 16 + r];
    }
    float lt0 = l_acc[0] + pr[32];
    float lt1 = l_acc[1] + pr[33];

    // epilogue: l = own + partner halves; each wave stores its dt=wk half
    for (int qs = 0; qs < 2; qs++) {
        float lts = qs == 0 ? lt0 : lt1;
        float ltot = lts + __shfl_xor(lts, 32, 64);
        float rl = 1.0f / ltot;
        int q = q0 + qs * 32 + l31;
        for (int g = 0; g < 4; g++)
            for (int r = 0; r < 4; r++) {
                int d = wk * 32 + 8 * g + 4 * hi + r;
                size_t gi = ((size_t)b * 512 + h * 64 + d) * 1024 + q;
                out[gi] = x[gi] + o[qs][g * 4 + r] * rl;
            }
    }
}

// ---------------------------------------------------------------------------
extern "C" void kernel_launch(void* const* d_in, const int* in_sizes, int n_in,
                              void* d_out, int out_size, void* d_ws, size_t ws_size,
                              hipStream_t stream) {
    (void)in_sizes; (void)n_in; (void)out_size; (void)ws_size;
    const float* x  = (const float*)d_in[0];
    const float* pv = (const float*)d_in[1];
    const float* pg = (const float*)d_in[2];
    const float* pb = (const float*)d_in[3];
    float* out = (float*)d_out;

    char* ws = (char*)d_ws;
    f16* w   = (f16*)(ws);                                   // 1,572,864 B
    f16* xT  = (f16*)(ws + 1572864);                         // 8,388,608 B
    f16* qk  = (f16*)(ws + 1572864 + 8388608);               // 16,777,216 B
    f16* v   = (f16*)(ws + 1572864 + 8388608 + 16777216);    // 8,388,608 B

    hipLaunchKernelGGL(prep_k,     dim3(5632),     dim3(256), 0, stream, pv, pg, w, x, xT);
    hipLaunchKernelGGL(qkv_gemm_k, dim3(8, 12, 8), dim3(256), 0, stream, w, xT, pb, qk, v);
    hipLaunchKernelGGL(attn_k,     dim3(64, 8),    dim3(256), 0, stream, qk, v, x, out);
}